// Round 5
// baseline (428.604 us; speedup 1.0000x reference)
//
#include <hip/hip_runtime.h>
#include <hip/hip_fp16.h>

// CapsuleLayer dynamic routing — round 9: direct VGPR-budget override.
// Rounds 6-8 post-mortem: the RA budget stuck at 84 VGPRs (6 waves/EU target)
// regardless of __launch_bounds__(TPB,1) or amdgpu_waves_per_eu(3,3) — both
// occupancy HINTS are inert on this toolchain, and the 120-reg hat2 array
// spills (WRITE_SIZE 286MB = scratch). amdgpu_num_vgpr(N) is not a hint: it is
// read directly as the register budget in getMaxNumVGPRs(), overriding the
// occupancy heuristic. 12 waves = 3/SIMD; 3x168 = 504 <= 512-reg file, demand
// ~150 <= 168. Everything else byte-identical to round 8 (isolate the variable).

#define IC 1152
#define IE 8
#define NC 10
#define DV 16
#define NB 256
#define NW (IC * NC * IE * DV)  // 1,474,560
#define SOUT (NC * DV)          // 160
#define NWAVE 12
#define TPB (NWAVE * 64)        // 768
#define NGPW 3                  // Gp groups per wave (36 = 12*3)

typedef _Float16 h2 __attribute__((ext_vector_type(2)));
union WChunk { int4 v; h2 p[4]; _Float16 h[8]; };
union XFrag { int4 v; h2 p[4]; };

#if defined(__has_builtin) && __has_builtin(__builtin_amdgcn_fdot2)
__device__ inline float fdot2(h2 a, h2 b, float c) {
    return __builtin_amdgcn_fdot2(a, b, c, false);
}
#else
__device__ inline float fdot2(h2 a, h2 b, float c) {
    return fmaf((float)a.x, (float)b.x, fmaf((float)a.y, (float)b.y, c));
}
#endif

// W fp32 [i][j][e][d] -> fp16 chunks Wc[((Gp*10+j)*8+k)*64 + lane], where
// lane = h*32+r, i = Gp*32+r, d = h*8+k; chunk holds e=0..7 halves of W[i,j,:,d].
__global__ void wprep_kernel(const float* __restrict__ W, int4* __restrict__ Wc) {
    const int t = blockIdx.x * blockDim.x + threadIdx.x;
    if (t >= NW / 8) return;
    const int lane = t & 63;
    const int h = lane >> 5, r = lane & 31;
    const int k = (t >> 6) & 7;
    const int r2 = t >> 9;  // Gp*10 + j
    const int j = r2 % NC, Gp = r2 / NC;
    const int i = Gp * 32 + r;
    const int d = h * 8 + k;
    const float* src = W + ((size_t)(i * NC + j) * IE) * DV + d;  // e-stride DV
    WChunk c;
#pragma unroll
    for (int e = 0; e < IE; ++e) c.h[e] = (_Float16)src[(size_t)e * DV];
    Wc[t] = c.v;
}

__global__ __launch_bounds__(TPB)
__attribute__((amdgpu_num_vgpr(168)))
void caps_kernel(
    const float* __restrict__ X,     // [B, IC, IE] fp32
    const int4* __restrict__ Wc,     // coalesced fp16 layout (see wprep)
    const float* __restrict__ bias,  // [IC*NC] fp32
    float* __restrict__ out)         // [B, NC, DV]
{
    // LDS: 46080 + 46080 + 4608 + 7680 + 640 + 320 = 105,408 B -> 1 block/CU
    __shared__ __align__(16) float bias_s[NC * IC];  // [j][i]
    __shared__ __align__(16) float U[NC * IC];       // union: packed-h2 X (hat phase) / exp(lt) table (rounds)
    __shared__ float Zs[IC];                         // 1/sum_j exp(lt)
    __shared__ float s_part[NWAVE * SOUT];           // per-wave exclusive s slabs
    __shared__ float vc[SOUT];                       // cumulative v (f32)
    __shared__ __align__(16) h2 v2[SOUT / 2];        // cumulative v packed for fdot2

    const int b = blockIdx.x;
    const int tid = threadIdx.x;
    const int w = tid >> 6;   // wave 0..11
    const int g = tid & 63;
    const int h = g >> 5;     // d-half: d = h*8 + k
    const int r = g & 31;     // row within 32-row group

    // ---- stage bias -> bias_s[j][i]; consecutive tid -> consecutive i
    // (conflict-free LDS writes; strided global read is 46KB from L2, cheap) ----
    for (int idx = tid; idx < IC * NC; idx += TPB) {  // 15 iters
        const int j = idx / IC, i = idx - j * IC;
        bias_s[idx] = bias[i * NC + j];
    }
    // ---- stage X[b] packed as h2 into U: 16B per row i ----
    {
        const float4* xb = (const float4*)(X + (size_t)b * IC * IE);
        h2* xp = (h2*)U;
        for (int f = tid; f < IC * IE / 4; f += TPB) {  // 2304 float4, 3 iters
            const float4 v = xb[f];
            xp[f * 2 + 0] = h2{(_Float16)v.x, (_Float16)v.y};
            xp[f * 2 + 1] = h2{(_Float16)v.z, (_Float16)v.w};
        }
    }
    __syncthreads();

    // ---- hat phase: stream W once, hat resident in regs (fp16, 120 VGPRs) ----
    h2 hat2[NGPW][NC][4];
    {
        const h2* xp = (const h2*)U;
#pragma unroll
        for (int gl = 0; gl < NGPW; ++gl) {
            const int Gp = NGPW * w + gl;
            const int i = Gp * 32 + r;
            XFrag xu;
            xu.v = *(const int4*)(xp + (size_t)i * 4);
#pragma unroll
            for (int j = 0; j < NC; ++j) {
                const int4* wp = Wc + ((size_t)(Gp * NC + j)) * 512 + g;
                float hat[8];
                WChunk wk[4];
#pragma unroll
                for (int k = 0; k < 4; ++k) wk[k].v = wp[k * 64];
#pragma unroll
                for (int k = 0; k < 4; ++k) {
                    float a = 0.f;
#pragma unroll
                    for (int q = 0; q < 4; ++q) a = fdot2(xu.p[q], wk[k].p[q], a);
                    hat[k] = a;
                }
#pragma unroll
                for (int k = 0; k < 4; ++k) wk[k].v = wp[(k + 4) * 64];
#pragma unroll
                for (int k = 0; k < 4; ++k) {
                    float a = 0.f;
#pragma unroll
                    for (int q = 0; q < 4; ++q) a = fdot2(xu.p[q], wk[k].p[q], a);
                    hat[k + 4] = a;
                }
#pragma unroll
                for (int q = 0; q < 4; ++q)
                    hat2[gl][j][q] = h2{(_Float16)hat[2 * q], (_Float16)hat[2 * q + 1]};
            }
        }
    }

    // ---- 3 routing rounds, fully in-LDS ----
    for (int rd = 0; rd < 3; ++rd) {
        __syncthreads();  // orders U readers (X / prev loop2) before U writes; v2 ready

        // loop1: logits -> exp table U[j][i]
        if (rd == 0) {
            for (int idx = tid; idx < IC * NC; idx += TPB)  // 15 iters
                U[idx] = __expf(bias_s[idx]);
        } else {
#pragma unroll
            for (int gl = 0; gl < NGPW; ++gl) {
                const int Gp = NGPW * w + gl;
                const int i = Gp * 32 + r;
#pragma unroll
                for (int j = 0; j < NC; ++j) {
                    XFrag vv;
                    vv.v = *(const int4*)(v2 + (j * 8 + h * 4));
                    float ah = 0.f;
#pragma unroll
                    for (int q = 0; q < 4; ++q) ah = fdot2(hat2[gl][j][q], vv.p[q], ah);
                    const float lt = bias_s[j * IC + i] + ah + __shfl_xor(ah, 32);
                    if (h == 0) U[j * IC + i] = __expf(lt);
                }
            }
        }
        __syncthreads();

        // Z pass: 1/sum_j exp  (2 iters per thread)
        for (int idx = tid; idx < IC; idx += TPB) {
            float Z = 0.f;
#pragma unroll
            for (int j = 0; j < NC; ++j) Z += U[j * IC + idx];
            Zs[idx] = 1.f / Z;
        }
        __syncthreads();

        // loop2: per-j accumulate c*hat over this wave's 3 Gp groups, one
        // butterfly per j, plain store into this wave's exclusive s_part slab
#pragma unroll
        for (int j = 0; j < NC; ++j) {
            float s8[8] = {0.f, 0.f, 0.f, 0.f, 0.f, 0.f, 0.f, 0.f};
#pragma unroll
            for (int gl = 0; gl < NGPW; ++gl) {
                const int Gp = NGPW * w + gl;
                const int i = Gp * 32 + r;
                const float c = U[j * IC + i] * Zs[i];
#pragma unroll
                for (int q = 0; q < 4; ++q) {
                    s8[2 * q]     = fmaf(c, (float)hat2[gl][j][q].x, s8[2 * q]);
                    s8[2 * q + 1] = fmaf(c, (float)hat2[gl][j][q].y, s8[2 * q + 1]);
                }
            }
            // splitting butterfly over the 32 r-lanes of this d-half: 8->4->2->1
            float t4[4];
#pragma unroll
            for (int d = 0; d < 4; ++d) {
                const bool hi = (r & 16);
                const float mine = hi ? s8[d + 4] : s8[d];
                const float send = hi ? s8[d] : s8[d + 4];
                t4[d] = mine + __shfl_xor(send, 16);
            }
            float t2[2];
#pragma unroll
            for (int d = 0; d < 2; ++d) {
                const bool hi = (r & 8);
                const float mine = hi ? t4[d + 2] : t4[d];
                const float send = hi ? t4[d] : t4[d + 2];
                t2[d] = mine + __shfl_xor(send, 8);
            }
            float t1;
            {
                const bool hi = (r & 4);
                const float mine = hi ? t2[1] : t2[0];
                const float send = hi ? t2[0] : t2[1];
                t1 = mine + __shfl_xor(send, 4);
            }
            t1 += __shfl_xor(t1, 2);
            t1 += __shfl_xor(t1, 1);
            if ((r & 3) == 0) {
                const int dl = (r >> 2) & 7;  // bit map: r4->d2, r3->d1, r2->d0
                s_part[w * SOUT + j * DV + h * 8 + dl] = t1;
            }
        }
        __syncthreads();

        // squash: sum the 12 wave slabs, squash, update cumulative v / output
        if (tid < SOUT) {
            float sv = 0.f;
#pragma unroll
            for (int ww = 0; ww < NWAVE; ++ww) sv += s_part[ww * SOUT + tid];
            float s2 = sv * sv;
#pragma unroll
            for (int mk = 8; mk >= 1; mk >>= 1) s2 += __shfl_xor(s2, mk, 16);
            const float scale = sqrtf(s2) / (1.f + s2);
            const float vv = scale * sv;
            if (rd == 2) {
                out[(size_t)b * SOUT + tid] = vv;
            } else {
                const float vcum = (rd == 0) ? vv : (vc[tid] + vv);
                vc[tid] = vcum;
                const float oth = __shfl_xor(vcum, 1);
                if (!(tid & 1)) v2[tid >> 1] = h2{(_Float16)vcum, (_Float16)oth};
            }
        }
    }
}

extern "C" void kernel_launch(void* const* d_in, const int* in_sizes, int n_in,
                              void* d_out, int out_size, void* d_ws, size_t ws_size,
                              hipStream_t stream) {
    const float* X = (const float*)d_in[0];     // [256,1152,8]
    const float* W = (const float*)d_in[1];     // [1152,10,8,16]
    const float* bias = (const float*)d_in[2];  // [1,1152,10]
    float* out = (float*)d_out;

    int4* Wc = (int4*)d_ws;  // ws: Wc only (2.95 MB)

    wprep_kernel<<<dim3(720), dim3(256), 0, stream>>>(W, Wc);
    caps_kernel<<<dim3(NB), dim3(TPB), 0, stream>>>(X, Wc, bias, out);
}

// Round 6
// 147.700 us; speedup vs baseline: 2.9019x; 2.9019x over previous
//
#include <hip/hip_runtime.h>
#include <hip/hip_fp16.h>

// CapsuleLayer dynamic routing — round 10: no big per-thread arrays, ever.
// Rounds 6-9 post-mortem: three register-budget knobs (launch_bounds min,
// waves_per_eu(3,3), amdgpu_num_vgpr(168)) produced BIT-IDENTICAL scratch
// traffic (WRITE_SIZE 279,712 KB each) -> the 480B/thread hat2 array was never
// promoted by SROA; budget attributes can't help an un-promoted alloca. The
// kernel was 100% scratch-HBM-bound (597MB/dispatch ~ 357us @ 1.6TB/s).
// New structure: softmax over j=10 is THREAD-LOCAL (a thread owns all 10 j's
// for its row/d-half) -> no LDS logit table, no barriers in the hot loop, and
// hat is only needed 40 regs at a time (per Gp-slice). Full hat lives in the
// WORKSPACE as fp16 (94MB, L3-resident): written once (fused with round 0),
// read once per later round. 4 launches, no atomics. Runtime ws-size guard
// falls back to recomputing hat from X*W per round if ws is too small.

#define IC 1152
#define IE 8
#define NC 10
#define DV 16
#define NB 256
#define NW (IC * NC * IE * DV)   // 1,474,560
#define SOUT (NC * DV)           // 160
#define NWAVE 12
#define TPB (NWAVE * 64)         // 768
#define NGPW 3                   // Gp groups per wave (36 = 12*3)
#define NPAIRB ((IC / 32) * NC)  // 360 pairs per batch element

typedef _Float16 h2 __attribute__((ext_vector_type(2)));
union WChunk { int4 v; h2 p[4]; _Float16 h[8]; };
union XFrag { int4 v; h2 p[4]; };

#if defined(__has_builtin) && __has_builtin(__builtin_amdgcn_fdot2)
__device__ inline float fdot2(h2 a, h2 b, float c) {
    return __builtin_amdgcn_fdot2(a, b, c, false);
}
#else
__device__ inline float fdot2(h2 a, h2 b, float c) {
    return fmaf((float)a.x, (float)b.x, fmaf((float)a.y, (float)b.y, c));
}
#endif

// W fp32 [i][j][e][d] -> fp16 chunks Wc[((Gp*10+j)*8+k)*64 + lane], where
// lane = h*32+r, i = Gp*32+r, d = h*8+k; chunk holds e=0..7 halves of W[i,j,:,d].
__global__ void wprep_kernel(const float* __restrict__ W, int4* __restrict__ Wc) {
    const int t = blockIdx.x * blockDim.x + threadIdx.x;
    if (t >= NW / 8) return;
    const int lane = t & 63;
    const int h = lane >> 5, r = lane & 31;
    const int k = (t >> 6) & 7;
    const int r2 = t >> 9;  // Gp*10 + j
    const int j = r2 % NC, Gp = r2 / NC;
    const int i = Gp * 32 + r;
    const int d = h * 8 + k;
    const float* src = W + ((size_t)(i * NC + j) * IE) * DV + d;  // e-stride DV
    WChunk c;
#pragma unroll
    for (int e = 0; e < IE; ++e) c.h[e] = (_Float16)src[(size_t)e * DV];
    Wc[t] = c.v;
}

// One routing round. Block = one batch element b; wave w owns Gp in
// {3w..3w+2}; lane g = h*32+r covers row i=Gp*32+r, d-half h. Per Gp-slice a
// thread holds hat for all 10 j (40 h2 regs max, short-lived) -> softmax over
// j is thread-local (no LDS, no barrier). Per-wave exclusive s_part slabs;
// squash fused at the end.
// RD=0: compute hat from X*Wc (c = softmax(bias)); optionally store hat (fp16).
// RD=1: hat from ws (or recompute); v_in=v1; writes vsum = v1 + squash(s1).
// RD=2: hat from ws (or recompute); v_in=vsum; writes final output.
template <int RD, bool HSTORE, bool HLOAD>
__global__ __launch_bounds__(TPB) void round_caps(
    const float* __restrict__ X,     // [B, IC, IE] fp32
    const int4* __restrict__ Wc,     // coalesced fp16 W (see wprep)
    const float* __restrict__ bias,  // [IC*NC] fp32
    int4* __restrict__ hat_ws,       // [B*360*64] int4 (fp16 hat) or unused
    const float* __restrict__ v_in,  // [B*160] or unused
    float* __restrict__ v_out)       // [B*160] (v1 / vsum / final out)
{
    __shared__ float s_part[NWAVE * SOUT];      // per-wave exclusive slabs
    __shared__ __align__(16) h2 v2s[SOUT / 2];  // v_in packed for fdot2

    const int b = blockIdx.x;
    const int tid = threadIdx.x;
    const int w = tid >> 6;  // wave 0..11
    const int g = tid & 63;
    const int h = g >> 5;    // d-half: d = h*8 + k
    const int r = g & 31;    // row within 32-row group

    float vkeep = 0.f;  // v1 value carried to the vsum write (RD==1)
    if constexpr (RD > 0) {
        if (RD == 1 && tid < SOUT) vkeep = v_in[(size_t)b * SOUT + tid];
        if (tid < SOUT / 2) {
            const float* vp = v_in + (size_t)b * SOUT + 2 * tid;
            v2s[tid] = h2{(_Float16)vp[0], (_Float16)vp[1]};
        }
    }
    // zero own slab (wave-private: no barrier needed before accumulation)
    for (int idx = g; idx < SOUT; idx += 64) s_part[w * SOUT + idx] = 0.f;
    if constexpr (RD > 0) __syncthreads();  // v2s ready

#pragma unroll
    for (int gl = 0; gl < NGPW; ++gl) {
        const int Gp = NGPW * w + gl;
        const int i = Gp * 32 + r;

        // ---- hat for all 10 j of this slice (40 h2 regs, slice-scoped) ----
        h2 hat2[NC][4];
        if constexpr (HLOAD) {
            const int4* hp = hat_ws + ((size_t)b * NPAIRB + Gp * NC) * 64 + g;
#pragma unroll
            for (int j = 0; j < NC; ++j) {
                WChunk u;
                u.v = hp[j * 64];
#pragma unroll
                for (int q = 0; q < 4; ++q) hat2[j][q] = u.p[q];
            }
        } else {
            XFrag xu;
            {
                const float4* xr = (const float4*)(X + ((size_t)b * IC + i) * IE);
                const float4 x0 = xr[0], x1 = xr[1];
                xu.p[0] = h2{(_Float16)x0.x, (_Float16)x0.y};
                xu.p[1] = h2{(_Float16)x0.z, (_Float16)x0.w};
                xu.p[2] = h2{(_Float16)x1.x, (_Float16)x1.y};
                xu.p[3] = h2{(_Float16)x1.z, (_Float16)x1.w};
            }
#pragma unroll
            for (int j = 0; j < NC; ++j) {
                const int4* wp = Wc + ((size_t)(Gp * NC + j)) * 512 + g;
                WChunk wk[4];
                float hat[8];
#pragma unroll
                for (int k = 0; k < 4; ++k) wk[k].v = wp[k * 64];
#pragma unroll
                for (int k = 0; k < 4; ++k) {
                    float a = 0.f;
#pragma unroll
                    for (int q = 0; q < 4; ++q) a = fdot2(xu.p[q], wk[k].p[q], a);
                    hat[k] = a;
                }
#pragma unroll
                for (int k = 0; k < 4; ++k) wk[k].v = wp[(k + 4) * 64];
#pragma unroll
                for (int k = 0; k < 4; ++k) {
                    float a = 0.f;
#pragma unroll
                    for (int q = 0; q < 4; ++q) a = fdot2(xu.p[q], wk[k].p[q], a);
                    hat[k + 4] = a;
                }
#pragma unroll
                for (int q = 0; q < 4; ++q)
                    hat2[j][q] = h2{(_Float16)hat[2 * q], (_Float16)hat[2 * q + 1]};
                if constexpr (HSTORE) {
                    WChunk u;
#pragma unroll
                    for (int q = 0; q < 4; ++q) u.p[q] = hat2[j][q];
                    hat_ws[((size_t)b * NPAIRB + Gp * NC + j) * 64 + g] = u.v;
                }
            }
        }

        // ---- logits + THREAD-LOCAL softmax over j ----
        float c[NC];
        {
            float Z = 0.f;
#pragma unroll
            for (int j = 0; j < NC; ++j) {
                float lt = bias[i * NC + j];
                if constexpr (RD > 0) {
                    XFrag vv;
                    vv.v = *(const int4*)(v2s + (j * 8 + h * 4));
                    float ah = 0.f;
#pragma unroll
                    for (int q = 0; q < 4; ++q) ah = fdot2(hat2[j][q], vv.p[q], ah);
                    lt += ah + __shfl_xor(ah, 32);  // combine d-halves
                }
                const float e = __expf(lt);
                c[j] = e;
                Z += e;
            }
            const float rz = 1.f / Z;
#pragma unroll
            for (int j = 0; j < NC; ++j) c[j] *= rz;
        }

        // ---- weighted sum: butterfly over 32 r-lanes per j, += wave slab ----
#pragma unroll
        for (int j = 0; j < NC; ++j) {
            float s8[8];
#pragma unroll
            for (int q = 0; q < 4; ++q) {
                s8[2 * q]     = c[j] * (float)hat2[j][q].x;
                s8[2 * q + 1] = c[j] * (float)hat2[j][q].y;
            }
            float t4[4];
#pragma unroll
            for (int d = 0; d < 4; ++d) {
                const bool hi = (r & 16);
                const float mine = hi ? s8[d + 4] : s8[d];
                const float send = hi ? s8[d] : s8[d + 4];
                t4[d] = mine + __shfl_xor(send, 16);
            }
            float t2[2];
#pragma unroll
            for (int d = 0; d < 2; ++d) {
                const bool hi = (r & 8);
                const float mine = hi ? t4[d + 2] : t4[d];
                const float send = hi ? t4[d] : t4[d + 2];
                t2[d] = mine + __shfl_xor(send, 8);
            }
            float t1;
            {
                const bool hi = (r & 4);
                const float mine = hi ? t2[1] : t2[0];
                const float send = hi ? t2[0] : t2[1];
                t1 = mine + __shfl_xor(send, 4);
            }
            t1 += __shfl_xor(t1, 2);
            t1 += __shfl_xor(t1, 1);
            if ((r & 3) == 0) {
                const int dl = (r >> 2) & 7;  // bit map: r4->d2, r3->d1, r2->d0
                s_part[w * SOUT + j * DV + h * 8 + dl] += t1;
            }
        }
    }
    __syncthreads();

    // ---- reduce slabs + squash (+ v1 add for vsum) ----
    if (tid < SOUT) {
        float sv = 0.f;
#pragma unroll
        for (int ww = 0; ww < NWAVE; ++ww) sv += s_part[ww * SOUT + tid];
        float s2 = sv * sv;
#pragma unroll
        for (int mk = 8; mk >= 1; mk >>= 1) s2 += __shfl_xor(s2, mk, 16);
        const float scale = sqrtf(s2) / (1.f + s2);
        float vv = scale * sv;
        if constexpr (RD == 1) vv += vkeep;  // vsum = v1 + v2
        v_out[(size_t)b * SOUT + tid] = vv;
    }
}

extern "C" void kernel_launch(void* const* d_in, const int* in_sizes, int n_in,
                              void* d_out, int out_size, void* d_ws, size_t ws_size,
                              hipStream_t stream) {
    const float* X = (const float*)d_in[0];     // [256,1152,8]
    const float* W = (const float*)d_in[1];     // [1152,10,8,16]
    const float* bias = (const float*)d_in[2];  // [1,1152,10]
    float* out = (float*)d_out;

    // ws layout: Wc (2.95MB) | v1 (160KB) | vsum (160KB) | hat (94.4MB)
    int4* Wc = (int4*)d_ws;
    float* v1 = (float*)(Wc + NW / 8);
    float* vsum = v1 + (size_t)NB * SOUT;
    int4* hat_ws = (int4*)(vsum + (size_t)NB * SOUT);
    const size_t need = (size_t)(NW / 8) * 16 + 2ull * NB * SOUT * 4 +
                        (size_t)NB * NPAIRB * 64 * 16;

    wprep_kernel<<<dim3(720), dim3(256), 0, stream>>>(W, Wc);

    dim3 grid(NB);
    if (ws_size >= need) {
        // store hat once, stream it from L3 in rounds 1-2
        round_caps<0, true, false><<<grid, TPB, 0, stream>>>(X, Wc, bias, hat_ws, nullptr, v1);
        round_caps<1, false, true><<<grid, TPB, 0, stream>>>(X, Wc, bias, hat_ws, v1, vsum);
        round_caps<2, false, true><<<grid, TPB, 0, stream>>>(X, Wc, bias, hat_ws, vsum, out);
    } else {
        // fallback: recompute hat from X*W each round (no hat storage)
        round_caps<0, false, false><<<grid, TPB, 0, stream>>>(X, Wc, bias, nullptr, nullptr, v1);
        round_caps<1, false, false><<<grid, TPB, 0, stream>>>(X, Wc, bias, nullptr, v1, vsum);
        round_caps<2, false, false><<<grid, TPB, 0, stream>>>(X, Wc, bias, nullptr, vsum, out);
    }
}